// Round 3
// baseline (298.936 us; speedup 1.0000x reference)
//
#include <hip/hip_runtime.h>

// VQ embedding, bf16-MFMA, occupancy-optimized.
// z: (B=64, D=256, H=32, W=32) fp32; codebook: (K=1024, D=256) fp32.
// argmin_k ||z_n - c_k||^2 = argmin_k (||c_k||^2 - 2 z.c_k).
// Outputs (flat fp32): st[16777216] = chosen codebook row, indices[65536] as float,
// loss = 1.25 * (sum z^2 + sum best_score).

#define IDX_OFF  16777216
#define LOSS_OFF 16842752

typedef __bf16 bf16x8 __attribute__((ext_vector_type(8)));
typedef float  f32x4  __attribute__((ext_vector_type(4)));

// ---------------- Kernel 1: cb fp32 -> bf16 copy + row norms (64 blocks) ----------------
__global__ __launch_bounds__(256) void vq_prep(const float* __restrict__ cb,
                                               __bf16* __restrict__ cbh,
                                               float* __restrict__ sc) {
    const int t = threadIdx.x;
    const int r = blockIdx.x * 16 + (t >> 4);
    const int d0 = (t & 15) * 16;
    const float* src = cb + (size_t)r * 256 + d0;
    __bf16* dst = cbh + (size_t)r * 256 + d0;
    float s = 0.f;
    float4 f[4];
    #pragma unroll
    for (int p = 0; p < 4; p++) f[p] = *(const float4*)(src + p * 4);
    bf16x8 v0, v1;
    #pragma unroll
    for (int p = 0; p < 4; p++) {
        s = fmaf(f[p].x, f[p].x, s); s = fmaf(f[p].y, f[p].y, s);
        s = fmaf(f[p].z, f[p].z, s); s = fmaf(f[p].w, f[p].w, s);
    }
    v0[0]=(__bf16)f[0].x; v0[1]=(__bf16)f[0].y; v0[2]=(__bf16)f[0].z; v0[3]=(__bf16)f[0].w;
    v0[4]=(__bf16)f[1].x; v0[5]=(__bf16)f[1].y; v0[6]=(__bf16)f[1].z; v0[7]=(__bf16)f[1].w;
    v1[0]=(__bf16)f[2].x; v1[1]=(__bf16)f[2].y; v1[2]=(__bf16)f[2].z; v1[3]=(__bf16)f[2].w;
    v1[4]=(__bf16)f[3].x; v1[5]=(__bf16)f[3].y; v1[6]=(__bf16)f[3].z; v1[7]=(__bf16)f[3].w;
    *(bf16x8*)dst = v0;
    *(bf16x8*)(dst + 8) = v1;
    s += __shfl_xor(s, 1, 64);
    s += __shfl_xor(s, 2, 64);
    s += __shfl_xor(s, 4, 64);
    s += __shfl_xor(s, 8, 64);
    if ((t & 15) == 0) sc[r] = s;
}

// ---------------- Kernel 2: MFMA distance-GEMM + argmin + outputs ----------------
// Block: 64 n-rows x all 1024 codes; 4 waves, wave w owns codes [w*256, w*256+256).
// LDS 32 KB (4 blocks/CU): z tile [64 n][256 d] bf16, XOR-swizzled 16B groups.
// Recycled after GEMM as argmin scratch, then as chosen-q tile for coalesced emit.
__global__ __launch_bounds__(256, 4) void vq_mfma(const float* __restrict__ z,
                                                  const __bf16* __restrict__ cbh,
                                                  const float* __restrict__ sc,
                                                  float* __restrict__ out,
                                                  float* __restrict__ partial) {
    __shared__ __align__(16) __bf16 z_s[64 * 256];   // 32768 B

    const int t    = threadIdx.x;
    const int lane = t & 63;
    const int w    = t >> 6;
    const int m16  = lane & 15;
    const int q4   = lane >> 4;
    const int blk  = blockIdx.x;
    const int b    = blk >> 4;
    const int hw0  = (blk & 15) << 6;
    const int n0   = blk << 6;

    // ---- phase A: stage z (fp32, coalesced) -> bf16 LDS [n][d]; accumulate sum z^2
    float lz = 0.f;
    {
        const int nl = t & 63;
        const int dq = (t >> 6) << 6;   // 0,64,128,192
        const float* zp = z + (size_t)(b * 256 + dq) * 1024 + hw0 + nl;
        #pragma unroll
        for (int p = 0; p < 8; p++) {
            bf16x8 v;
            #pragma unroll
            for (int j = 0; j < 8; j++) {
                float f = zp[(size_t)(p * 8 + j) * 1024];
                lz = fmaf(f, f, lz);
                v[j] = (__bf16)f;
            }
            int gs = ((dq >> 3) + p) ^ (nl & 7);
            *(bf16x8*)&z_s[nl * 256 + gs * 8] = v;
        }
    }
    __syncthreads();

    // ---- GEMM + running argmin (no barriers in this loop)
    float bestv[16];
    int   bestk[16];
    #pragma unroll
    for (int i = 0; i < 16; i++) { bestv[i] = 3.4e38f; bestk[i] = 0; }

    const int kbase = w << 8;           // wave's 256-code range
    #pragma unroll 1
    for (int kc0 = 0; kc0 < 256; kc0 += 64) {
        const __bf16* bp0 = cbh + (size_t)(kbase + kc0 + m16) * 256 + q4 * 8;
        f32x4 acc[4][4];
        #pragma unroll
        for (int i = 0; i < 4; i++)
            #pragma unroll
            for (int j = 0; j < 4; j++) acc[i][j] = (f32x4){0.f, 0.f, 0.f, 0.f};

        #pragma unroll
        for (int dc = 0; dc < 256; dc += 32) {
            bf16x8 a[4], bb[4];
            const int gs = ((dc >> 3) + q4) ^ (m16 & 7);
            #pragma unroll
            for (int i = 0; i < 4; i++)
                a[i] = *(const bf16x8*)&z_s[(m16 + i * 16) * 256 + gs * 8];
            #pragma unroll
            for (int j = 0; j < 4; j++)
                bb[j] = *(const bf16x8*)(bp0 + (size_t)j * 16 * 256 + dc);
            #pragma unroll
            for (int i = 0; i < 4; i++)
                #pragma unroll
                for (int j = 0; j < 4; j++)
                    acc[i][j] = __builtin_amdgcn_mfma_f32_16x16x32_bf16(a[i], bb[j], acc[i][j], 0, 0, 0);
        }
        // score = ||c||^2 - 2 z.c
        #pragma unroll
        for (int j = 0; j < 4; j++) {
            int kc = kbase + kc0 + j * 16 + m16;
            float sck = sc[kc];
            #pragma unroll
            for (int i = 0; i < 4; i++)
                #pragma unroll
                for (int r = 0; r < 4; r++) {
                    float v2 = fmaf(-2.f, acc[i][j][r], sck);
                    int pos = i * 4 + r;
                    if (v2 < bestv[pos]) { bestv[pos] = v2; bestk[pos] = kc; }
                }
        }
    }

    // ---- intra-wave argmin across the 16 col-lanes (first-index tie-break)
    #pragma unroll
    for (int pos = 0; pos < 16; pos++) {
        float v = bestv[pos]; int k = bestk[pos];
        #pragma unroll
        for (int off = 1; off < 16; off <<= 1) {
            float vo = __shfl_xor(v, off, 64);
            int   ko = __shfl_xor(k, off, 64);
            if (vo < v || (vo == v && ko < k)) { v = vo; k = ko; }
        }
        bestv[pos] = v; bestk[pos] = k;
    }
    __syncthreads();              // z_s reads done -> becomes scratch

    // ---- phase B: cross-wave combine (waves own disjoint ascending k-ranges)
    float* fs = (float*)z_s;      // fs[w*64+row]: best val; is[256+w*64+row]: best k
    int*   is = (int*)z_s;        // fs[512..576): chosen k as float; fs[640..644): red
    if (m16 == 0) {
        #pragma unroll
        for (int pos = 0; pos < 16; pos++) {
            int i = pos >> 2, r = pos & 3;
            int row = i * 16 + q4 * 4 + r;
            fs[w * 64 + row] = bestv[pos];
            is[256 + w * 64 + row] = bestk[pos];
        }
    }
    __syncthreads();
    if (t < 64) {
        float v = fs[t];
        int   k = is[256 + t];
        #pragma unroll
        for (int ww = 1; ww < 4; ww++) {
            float vw = fs[ww * 64 + t];
            int   kw = is[256 + ww * 64 + t];
            if (vw < v) { v = vw; k = kw; }   // ties keep lower w -> lower k
        }
        fs[512 + t] = (float)k;
        out[IDX_OFF + n0 + t] = (float)k;
        lz += v;                               // loss += best score for this row
    }
    {
        float s = lz;
        #pragma unroll
        for (int off = 1; off < 64; off <<= 1) s += __shfl_xor(s, off, 64);
        if (lane == 0) fs[640 + w] = s;
    }
    __syncthreads();
    if (t == 0) partial[blk] = (fs[640] + fs[641]) + (fs[642] + fs[643]);

    // ---- phase C: stage chosen codebook rows, then coalesced emit
    const int qrow = t >> 2;
    const int qoff = (t & 3) * 64;
    const int myk  = (int)fs[512 + qrow];
    __syncthreads();              // kf read by all -> safe to overwrite z_s
    {
        const __bf16* qp = cbh + (size_t)myk * 256 + qoff;
        #pragma unroll
        for (int p = 0; p < 8; p++) {
            bf16x8 v = *(const bf16x8*)(qp + p * 8);
            int gs = ((qoff >> 3) + p) ^ (qrow & 7);
            *(bf16x8*)&z_s[qrow * 256 + gs * 8] = v;
        }
    }
    __syncthreads();
    {
        const int nl = t & 63;
        const int dq = (t >> 6) << 6;
        float* op = out + (size_t)(b * 256 + dq) * 1024 + hw0 + nl;
        #pragma unroll
        for (int p = 0; p < 8; p++) {
            int gs = ((dq >> 3) + p) ^ (nl & 7);
            bf16x8 v = *(const bf16x8*)&z_s[nl * 256 + gs * 8];
            #pragma unroll
            for (int j = 0; j < 8; j++)
                op[(size_t)(p * 8 + j) * 1024] = (float)v[j];
        }
    }
}

// ---------------- Kernel 3: loss reduction over 1024 block partials ----------------
__global__ __launch_bounds__(256) void vq_loss_reduce(const float* __restrict__ partial,
                                                      float* __restrict__ out) {
    __shared__ float r_s[4];
    const int t = threadIdx.x;
    float s = (partial[t] + partial[t + 256]) + (partial[t + 512] + partial[t + 768]);
    #pragma unroll
    for (int off = 1; off < 64; off <<= 1) s += __shfl_xor(s, off, 64);
    if ((t & 63) == 0) r_s[t >> 6] = s;
    __syncthreads();
    if (t == 0) out[LOSS_OFF] = 1.25f * ((r_s[0] + r_s[1]) + (r_s[2] + r_s[3]));
}

extern "C" void kernel_launch(void* const* d_in, const int* in_sizes, int n_in,
                              void* d_out, int out_size, void* d_ws, size_t ws_size,
                              hipStream_t stream) {
    const float* z  = (const float*)d_in[0];   // 16777216
    const float* cb = (const float*)d_in[1];   // 262144
    float* out = (float*)d_out;

    float*  sc      = (float*)d_ws;                        // 1024 f
    float*  partial = sc + 1024;                           // 1024 f
    __bf16* cbh     = (__bf16*)((char*)d_ws + 8192);       // 512 KB

    vq_prep<<<64, 256, 0, stream>>>(cb, cbh, sc);
    vq_mfma<<<1024, 256, 0, stream>>>(z, cbh, sc, out, partial);
    vq_loss_reduce<<<1, 256, 0, stream>>>(partial, out);
}

// Round 4
// 192.839 us; speedup vs baseline: 1.5502x; 1.5502x over previous
//
#include <hip/hip_runtime.h>

// VQ embedding, bf16-MFMA, register-pipelined B + packed uint argmin.
// z: (B=64, D=256, H=32, W=32) fp32; codebook: (K=1024, D=256) fp32.
// argmin_k ||z_n - c_k||^2 = argmin_k (1 + ||c_k||^2 - 2 z.c_k)   [shift keeps score > 0]
// Packed key: (float_bits(score) & 0xFFFFFC00) | k  -> uint min = argmin w/ first-index ties.
// Outputs (flat fp32): st[16777216] = chosen codebook row, indices[65536] as float,
// loss = 1.25 * (sum z^2 + sum (best_score - 1)).

#define IDX_OFF  16777216
#define LOSS_OFF 16842752

typedef __bf16 bf16x8 __attribute__((ext_vector_type(8)));
typedef float  f32x4  __attribute__((ext_vector_type(4)));

// ---------------- Kernel 1: cb fp32 -> bf16 copy + (1 + row norm) ----------------
__global__ __launch_bounds__(256) void vq_prep(const float* __restrict__ cb,
                                               __bf16* __restrict__ cbh,
                                               float* __restrict__ sc1) {
    const int t = threadIdx.x;
    const int r = blockIdx.x * 16 + (t >> 4);
    const int d0 = (t & 15) * 16;
    const float* src = cb + (size_t)r * 256 + d0;
    __bf16* dst = cbh + (size_t)r * 256 + d0;
    float s = 0.f;
    float4 f[4];
    #pragma unroll
    for (int p = 0; p < 4; p++) f[p] = *(const float4*)(src + p * 4);
    bf16x8 v0, v1;
    #pragma unroll
    for (int p = 0; p < 4; p++) {
        s = fmaf(f[p].x, f[p].x, s); s = fmaf(f[p].y, f[p].y, s);
        s = fmaf(f[p].z, f[p].z, s); s = fmaf(f[p].w, f[p].w, s);
    }
    v0[0]=(__bf16)f[0].x; v0[1]=(__bf16)f[0].y; v0[2]=(__bf16)f[0].z; v0[3]=(__bf16)f[0].w;
    v0[4]=(__bf16)f[1].x; v0[5]=(__bf16)f[1].y; v0[6]=(__bf16)f[1].z; v0[7]=(__bf16)f[1].w;
    v1[0]=(__bf16)f[2].x; v1[1]=(__bf16)f[2].y; v1[2]=(__bf16)f[2].z; v1[3]=(__bf16)f[2].w;
    v1[4]=(__bf16)f[3].x; v1[5]=(__bf16)f[3].y; v1[6]=(__bf16)f[3].z; v1[7]=(__bf16)f[3].w;
    *(bf16x8*)dst = v0;
    *(bf16x8*)(dst + 8) = v1;
    s += __shfl_xor(s, 1, 64);
    s += __shfl_xor(s, 2, 64);
    s += __shfl_xor(s, 4, 64);
    s += __shfl_xor(s, 8, 64);
    if ((t & 15) == 0) sc1[r] = s + 1.0f;
}

// ---------------- Kernel 2: MFMA distance-GEMM + argmin + outputs ----------------
// Block: 128 n-rows x all 1024 codes. 4 waves: wn=(w>>1)*64 rows, wk=(w&1)*64 codes
// of each 128-wide kt chunk. LDS 64 KB z tile [128][256] bf16, XOR-swizzled; recycled
// as argmin scratch, then as chosen-q tile for coalesced emit. No barriers in K-loop;
// B-frags register-double-buffered from L2-resident bf16 codebook.
__global__ __launch_bounds__(256, 2) void vq_mfma(const float* __restrict__ z,
                                                  const __bf16* __restrict__ cbh,
                                                  const float* __restrict__ sc1,
                                                  float* __restrict__ out) {
    __shared__ __align__(16) __bf16 z_s[128 * 256];   // 65536 B
    __shared__ float red_s[4];

    const int t    = threadIdx.x;
    const int lane = t & 63;
    const int w    = t >> 6;
    const int m16  = lane & 15;
    const int q4   = lane >> 4;
    const int wn   = (w >> 1) * 64;
    const int wk   = (w & 1) * 64;
    const int blk  = blockIdx.x;
    const int b    = blk >> 3;
    const int hw0  = (blk & 7) << 7;
    const int n0   = blk << 7;

    // B double-buffer: preload kt=0 frags immediately (in flight during phase A)
    bf16x8 bb[4];
    {
        const __bf16* bp = cbh + (size_t)(wk + m16) * 256 + q4 * 8;
        #pragma unroll
        for (int j = 0; j < 4; j++) bb[j] = *(const bf16x8*)(bp + (size_t)j * 4096);
    }

    // ---- phase A: stage z (fp32 global, coalesced) -> bf16 LDS [n][d]; sum z^2
    float lz = 0.f;
    {
        const int nl    = t & 127;
        const int dhalf = (t >> 7) << 7;   // 0 or 128
        const float* zp = z + (size_t)(b * 256 + dhalf) * 1024 + hw0 + nl;
        #pragma unroll
        for (int p = 0; p < 16; p++) {
            bf16x8 v;
            #pragma unroll
            for (int j = 0; j < 8; j++) {
                float f = zp[(size_t)(p * 8 + j) * 1024];
                lz = fmaf(f, f, lz);
                v[j] = (__bf16)f;
            }
            int gs = ((dhalf >> 3) + p) ^ (nl & 7);
            *(bf16x8*)&z_s[nl * 256 + gs * 8] = v;
        }
    }
    __syncthreads();

    // ---- GEMM + packed-uint running argmin (no barriers, pipelined B)
    unsigned int best[16];
    #pragma unroll
    for (int i = 0; i < 16; i++) best[i] = 0xFFFFFFFFu;

    const int arow = wn + m16;
    #pragma unroll 1
    for (int kt = 0; kt < 1024; kt += 128) {
        // per-kt code norms (+1) and packed indices — loads hidden under MFMAs
        int   kcv[4];
        float sck[4];
        #pragma unroll
        for (int j = 0; j < 4; j++) {
            kcv[j] = kt + wk + j * 16 + m16;
            sck[j] = sc1[kcv[j]];
        }
        const __bf16* bc  = cbh + (size_t)(kt + wk + m16) * 256 + q4 * 8;
        const int ktn = (kt + 128) & 1023;
        const __bf16* bnx = cbh + (size_t)(ktn + wk + m16) * 256 + q4 * 8;

        f32x4 acc[4][4];
        #pragma unroll
        for (int i = 0; i < 4; i++)
            #pragma unroll
            for (int j = 0; j < 4; j++) acc[i][j] = (f32x4){0.f, 0.f, 0.f, 0.f};

        #pragma unroll
        for (int dc = 0; dc < 256; dc += 32) {
            // prefetch next chunk's B (next kt's dc=0 on the last chunk)
            bf16x8 bn[4];
            const __bf16* bp = (dc == 224) ? bnx : (bc + dc + 32);
            #pragma unroll
            for (int j = 0; j < 4; j++) bn[j] = *(const bf16x8*)(bp + (size_t)j * 4096);

            bf16x8 a[4];
            const int gs = ((dc >> 3) + q4) ^ (m16 & 7);
            #pragma unroll
            for (int i = 0; i < 4; i++)
                a[i] = *(const bf16x8*)&z_s[(arow + i * 16) * 256 + gs * 8];

            #pragma unroll
            for (int i = 0; i < 4; i++)
                #pragma unroll
                for (int j = 0; j < 4; j++)
                    acc[i][j] = __builtin_amdgcn_mfma_f32_16x16x32_bf16(a[i], bb[j], acc[i][j], 0, 0, 0);

            #pragma unroll
            for (int j = 0; j < 4; j++) bb[j] = bn[j];
        }

        // packed argmin: score = 1 + ||c||^2 - 2 z.c  > 0 always
        #pragma unroll
        for (int j = 0; j < 4; j++) {
            #pragma unroll
            for (int i = 0; i < 4; i++)
                #pragma unroll
                for (int r = 0; r < 4; r++) {
                    float v3 = fmaf(-2.f, acc[i][j][r], sck[j]);
                    unsigned int key = (__float_as_uint(v3) & 0xFFFFFC00u) | (unsigned int)kcv[j];
                    int pos = i * 4 + r;
                    best[pos] = min(best[pos], key);
                }
        }
    }

    // ---- intra-wave min across the 16 col-lanes
    #pragma unroll
    for (int pos = 0; pos < 16; pos++) {
        unsigned int k = best[pos];
        #pragma unroll
        for (int off = 1; off < 16; off <<= 1)
            k = min(k, (unsigned int)__shfl_xor((int)k, off, 64));
        best[pos] = k;
    }
    __syncthreads();              // all z_s reads done -> z_s becomes scratch

    // ---- cross-wave combine in recycled z_s
    unsigned int* ks = (unsigned int*)z_s;   // ks[0..256): key[slot][row]; ks[512..640): chosen k
    if (m16 == 0) {
        #pragma unroll
        for (int pos = 0; pos < 16; pos++) {
            int i = pos >> 2, r = pos & 3;
            int row = wn + i * 16 + q4 * 4 + r;
            ks[(w & 1) * 128 + row] = best[pos];
        }
    }
    __syncthreads();
    if (t < 128) {
        unsigned int key = min(ks[t], ks[128 + t]);
        int kf = (int)(key & 1023u);
        ks[512 + t] = (unsigned int)kf;
        out[IDX_OFF + n0 + t] = (float)kf;
        lz += __uint_as_float(key & 0xFFFFFC00u) - 1.0f;   // best score (unshifted)
    }
    {
        float s = lz;
        #pragma unroll
        for (int off = 1; off < 64; off <<= 1) s += __shfl_xor(s, off, 64);
        if (lane == 0) red_s[w] = s;
    }
    __syncthreads();              // ks[512..640) and red_s visible
    if (t == 0)
        atomicAdd(out + LOSS_OFF, 1.25f * ((red_s[0] + red_s[1]) + (red_s[2] + red_s[3])));

    // ---- stage chosen codebook rows into z_s, then coalesced emit
    const int qrow = t >> 1;
    const int qoff = (t & 1) * 128;
    const int myk  = (int)ks[512 + qrow];
    __syncthreads();              // everyone read their k; safe to overwrite z_s
    {
        const __bf16* qp = cbh + (size_t)myk * 256 + qoff;
        #pragma unroll
        for (int p = 0; p < 16; p++) {
            bf16x8 v = *(const bf16x8*)(qp + p * 8);
            int gs = ((qoff >> 3) + p) ^ (qrow & 7);
            *(bf16x8*)&z_s[qrow * 256 + gs * 8] = v;
        }
    }
    __syncthreads();
    {
        const int nl    = t & 127;
        const int dhalf = (t >> 7) << 7;
        float* op = out + (size_t)(b * 256 + dhalf) * 1024 + hw0 + nl;
        #pragma unroll
        for (int p = 0; p < 16; p++) {
            int gs = ((dhalf >> 3) + p) ^ (nl & 7);
            bf16x8 v = *(const bf16x8*)&z_s[nl * 256 + gs * 8];
            #pragma unroll
            for (int j = 0; j < 8; j++)
                op[(size_t)(p * 8 + j) * 1024] = (float)v[j];
        }
    }
}

extern "C" void kernel_launch(void* const* d_in, const int* in_sizes, int n_in,
                              void* d_out, int out_size, void* d_ws, size_t ws_size,
                              hipStream_t stream) {
    const float* z  = (const float*)d_in[0];   // 16777216
    const float* cb = (const float*)d_in[1];   // 262144
    float* out = (float*)d_out;

    float*  sc1 = (float*)d_ws;                        // 1024 f  (1 + ||c||^2)
    __bf16* cbh = (__bf16*)((char*)d_ws + 8192);       // 512 KB bf16 codebook

    hipMemsetAsync(out + LOSS_OFF, 0, sizeof(float), stream);   // capture-safe
    vq_prep<<<64, 256, 0, stream>>>(cb, cbh, sc1);
    vq_mfma<<<512, 256, 0, stream>>>(z, cbh, sc1, out);
}